// Round 1
// baseline (139.748 us; speedup 1.0000x reference)
//
#include <hip/hip_runtime.h>
#include <hip/hip_bf16.h>

// EmbeddingBag(mode='sum', include_last_offset=True) fused with the
// (F,B,D) -> (B,F,D) transpose.
//
// F=26, B=4096, D=64, NUM_BAGS=F*B=106496, V=2097152, VOCAB=2600000.
// bag = f*B + b ; out[b*F*D + f*D + d] = sum_{i in [off[bag],off[bag+1])} weight[values[i]][d]
//
// One wave (64 lanes) per bag. 4 row-groups x 16 lanes; lane handles
// float4 (16B) of one row -> 4 gathered rows in flight per iteration.
// Cross-row-group reduce with 2 shfl_xor steps; 16 lanes store 256B out row.

#define F_FEAT 26
#define B_BATCH 4096
#define D_DIM 64
#define NUM_BAGS (F_FEAT * B_BATCH)

__global__ __launch_bounds__(256) void embag_sum_kernel(
    const int* __restrict__ values,
    const int* __restrict__ offsets,
    const float* __restrict__ weight,
    float* __restrict__ out)
{
    const int wave = (int)((blockIdx.x * blockDim.x + threadIdx.x) >> 6);
    if (wave >= NUM_BAGS) return;
    const int lane = (int)(threadIdx.x & 63);
    const int rgrp = lane >> 4;      // 0..3 : which row (index) within a 4-chunk
    const int col4 = lane & 15;      // 0..15: which float4 of the 64-float row

    const int start = offsets[wave];
    const int end   = offsets[wave + 1];

    float4 acc = make_float4(0.f, 0.f, 0.f, 0.f);

    for (int i = start + rgrp; i < end; i += 4) {
        const int idx = values[i];
        const float4 w = *reinterpret_cast<const float4*>(
            weight + (size_t)idx * D_DIM + (col4 << 2));
        acc.x += w.x; acc.y += w.y; acc.z += w.z; acc.w += w.w;
    }

    // Reduce the 4 row-groups (lane bits 4 and 5) onto row-group 0.
    #pragma unroll
    for (int m = 16; m <= 32; m <<= 1) {
        acc.x += __shfl_xor(acc.x, m, 64);
        acc.y += __shfl_xor(acc.y, m, 64);
        acc.z += __shfl_xor(acc.z, m, 64);
        acc.w += __shfl_xor(acc.w, m, 64);
    }

    if (rgrp == 0) {
        const int f = wave >> 12;        // wave / B_BATCH (B=4096)
        const int b = wave & (B_BATCH - 1);
        float4* o = reinterpret_cast<float4*>(
            out + ((size_t)b * F_FEAT + f) * D_DIM);
        o[col4] = acc;
    }
}

extern "C" void kernel_launch(void* const* d_in, const int* in_sizes, int n_in,
                              void* d_out, int out_size, void* d_ws, size_t ws_size,
                              hipStream_t stream) {
    const int*   values  = (const int*)d_in[0];
    const int*   offsets = (const int*)d_in[1];
    const float* weight  = (const float*)d_in[2];
    float*       out     = (float*)d_out;

    // 4 waves per 256-thread block; NUM_BAGS = 106496 waves -> 26624 blocks.
    const int waves_per_block = 256 / 64;
    const int grid = (NUM_BAGS + waves_per_block - 1) / waves_per_block;
    embag_sum_kernel<<<grid, 256, 0, stream>>>(values, offsets, weight, out);
}

// Round 4
// 110.422 us; speedup vs baseline: 1.2656x; 1.2656x over previous
//
#include <hip/hip_runtime.h>
#include <hip/hip_bf16.h>

// EmbeddingBag(mode='sum', include_last_offset=True) fused with (F,B,D)->(B,F,D).
// F=26, B=4096, D=64, NUM_BAGS=106496, avg bag len ~19.7.
//
// One wave per bag. Indices prefetched 64-at-a-time with ONE coalesced load,
// then broadcast from registers via __shfl executed in WAVE-UNIFORM control
// flow (shfl from an exec-masked-off lane is undefined on CDNA — the R3 bug).
// Only the weight loads/accumulates are predicated. 4 row-groups x 16 lanes,
// float4 per lane, dual accumulators -> 8 independent 1KB row loads in flight.

#define F_FEAT 26
#define B_BATCH 4096
#define D_DIM 64
#define NUM_BAGS (F_FEAT * B_BATCH)

typedef float f32x4 __attribute__((ext_vector_type(4)));

__global__ __launch_bounds__(256) void embag_sum_kernel(
    const int* __restrict__ values,
    const int* __restrict__ offsets,
    const float* __restrict__ weight,
    float* __restrict__ out)
{
    const int wave = (int)((blockIdx.x * blockDim.x + threadIdx.x) >> 6);
    if (wave >= NUM_BAGS) return;
    const int lane = (int)(threadIdx.x & 63);
    const int rgrp = lane >> 4;      // 0..3 : row slot within an 8-row block
    const int col4 = lane & 15;      // 0..15: which float4 of the 64-float row

    const int start = offsets[wave];
    const int len   = offsets[wave + 1] - start;

    f32x4 acc0 = {0.f, 0.f, 0.f, 0.f};
    f32x4 acc1 = {0.f, 0.f, 0.f, 0.f};

    for (int base = 0; base < len; base += 64) {
        const int chunk = min(64, len - base);
        // One coalesced load grabs up to 64 indices for the whole wave.
        const int myidx = (lane < chunk) ? values[start + base + lane] : 0;

        // Wave-uniform loop: every lane runs the same rb iterations, so the
        // shfl sources are always active lanes. Loads are predicated.
        for (int rb = 0; rb < chunk; rb += 8) {
            const int r0 = rb + rgrp;       // <= 59
            const int r1 = rb + rgrp + 4;   // <= 63
            const int i0 = __shfl(myidx, r0, 64);
            const int i1 = __shfl(myidx, r1, 64);
            if (r0 < chunk) {
                acc0 += *reinterpret_cast<const f32x4*>(
                    weight + (size_t)i0 * D_DIM + (col4 << 2));
            }
            if (r1 < chunk) {
                acc1 += *reinterpret_cast<const f32x4*>(
                    weight + (size_t)i1 * D_DIM + (col4 << 2));
            }
        }
    }

    acc0 += acc1;

    // Reduce the 4 row-groups (lane bits 4 and 5) onto row-group 0.
    #pragma unroll
    for (int m = 16; m <= 32; m <<= 1) {
        acc0.x += __shfl_xor(acc0.x, m, 64);
        acc0.y += __shfl_xor(acc0.y, m, 64);
        acc0.z += __shfl_xor(acc0.z, m, 64);
        acc0.w += __shfl_xor(acc0.w, m, 64);
    }

    if (rgrp == 0) {
        const int f = wave >> 12;        // wave / B_BATCH (B=4096)
        const int b = wave & (B_BATCH - 1);
        f32x4* o = reinterpret_cast<f32x4*>(
            out + ((size_t)b * F_FEAT + f) * D_DIM);
        __builtin_nontemporal_store(acc0, &o[col4]);
    }
}

extern "C" void kernel_launch(void* const* d_in, const int* in_sizes, int n_in,
                              void* d_out, int out_size, void* d_ws, size_t ws_size,
                              hipStream_t stream) {
    const int*   values  = (const int*)d_in[0];
    const int*   offsets = (const int*)d_in[1];
    const float* weight  = (const float*)d_in[2];
    float*       out     = (float*)d_out;

    const int waves_per_block = 256 / 64;
    const int grid = (NUM_BAGS + waves_per_block - 1) / waves_per_block;
    embag_sum_kernel<<<grid, 256, 0, stream>>>(values, offsets, weight, out);
}

// Round 5
// 93.032 us; speedup vs baseline: 1.5021x; 1.1869x over previous
//
#include <hip/hip_runtime.h>
#include <hip/hip_bf16.h>

// EmbeddingBag(mode='sum', include_last_offset=True) fused with (F,B,D)->(B,F,D).
// F=26, B=4096, D=64, NUM_BAGS=106496, avg bag len ~19.7.
//
// One wave per bag. Indices prefetched 64-at-a-time with ONE coalesced load,
// broadcast from registers via __shfl in wave-uniform control flow.
// Row loop split: main loop over FULL 8-row blocks (no predication, loads
// form clean clauses) + one predicated tail block. 4 row-groups x 16 lanes,
// float4/lane, dual accumulator chains.

#define F_FEAT 26
#define B_BATCH 4096
#define D_DIM 64
#define NUM_BAGS (F_FEAT * B_BATCH)

typedef float f32x4 __attribute__((ext_vector_type(4)));

__global__ __launch_bounds__(256) void embag_sum_kernel(
    const int* __restrict__ values,
    const int* __restrict__ offsets,
    const float* __restrict__ weight,
    float* __restrict__ out)
{
    const int wave = (int)((blockIdx.x * blockDim.x + threadIdx.x) >> 6);
    if (wave >= NUM_BAGS) return;
    const int lane = (int)(threadIdx.x & 63);
    const int rgrp = lane >> 4;      // 0..3 : row slot within an 8-row block
    const int col4 = lane & 15;      // 0..15: which float4 of the 64-float row

    const int start = offsets[wave];
    const int len   = offsets[wave + 1] - start;

    f32x4 acc0 = {0.f, 0.f, 0.f, 0.f};
    f32x4 acc1 = {0.f, 0.f, 0.f, 0.f};

    for (int base = 0; base < len; base += 64) {
        const int chunk = min(64, len - base);
        // One coalesced load grabs up to 64 indices for the whole wave.
        const int myidx = (lane < chunk) ? values[start + base + lane] : 0;

        const int nfull = chunk & ~7;   // rows covered by full 8-row blocks
        int rb = 0;
        // Main loop: no predication, wave-uniform trip count.
        for (; rb < nfull; rb += 8) {
            const int i0 = __shfl(myidx, rb + rgrp, 64);
            const int i1 = __shfl(myidx, rb + rgrp + 4, 64);
            const f32x4 w0 = *reinterpret_cast<const f32x4*>(
                weight + (size_t)i0 * D_DIM + (col4 << 2));
            const f32x4 w1 = *reinterpret_cast<const f32x4*>(
                weight + (size_t)i1 * D_DIM + (col4 << 2));
            acc0 += w0;
            acc1 += w1;
        }
        // Tail block (0 < chunk-rb < 8): predicated loads, uniform shfl.
        if (rb < chunk) {
            const int r0 = rb + rgrp;
            const int r1 = rb + rgrp + 4;
            const int i0 = __shfl(myidx, r0, 64);
            const int i1 = __shfl(myidx, r1, 64);
            if (r0 < chunk) {
                acc0 += *reinterpret_cast<const f32x4*>(
                    weight + (size_t)i0 * D_DIM + (col4 << 2));
            }
            if (r1 < chunk) {
                acc1 += *reinterpret_cast<const f32x4*>(
                    weight + (size_t)i1 * D_DIM + (col4 << 2));
            }
        }
    }

    acc0 += acc1;

    // Reduce the 4 row-groups (lane bits 4 and 5) onto row-group 0.
    #pragma unroll
    for (int m = 16; m <= 32; m <<= 1) {
        acc0.x += __shfl_xor(acc0.x, m, 64);
        acc0.y += __shfl_xor(acc0.y, m, 64);
        acc0.z += __shfl_xor(acc0.z, m, 64);
        acc0.w += __shfl_xor(acc0.w, m, 64);
    }

    if (rgrp == 0) {
        const int f = wave >> 12;        // wave / B_BATCH (B=4096)
        const int b = wave & (B_BATCH - 1);
        f32x4* o = reinterpret_cast<f32x4*>(
            out + ((size_t)b * F_FEAT + f) * D_DIM);
        __builtin_nontemporal_store(acc0, &o[col4]);
    }
}

extern "C" void kernel_launch(void* const* d_in, const int* in_sizes, int n_in,
                              void* d_out, int out_size, void* d_ws, size_t ws_size,
                              hipStream_t stream) {
    const int*   values  = (const int*)d_in[0];
    const int*   offsets = (const int*)d_in[1];
    const float* weight  = (const float*)d_in[2];
    float*       out     = (float*)d_out;

    const int waves_per_block = 256 / 64;
    const int grid = (NUM_BAGS + waves_per_block - 1) / waves_per_block;
    embag_sum_kernel<<<grid, 256, 0, stream>>>(values, offsets, weight, out);
}

// Round 6
// 88.470 us; speedup vs baseline: 1.5796x; 1.0516x over previous
//
#include <hip/hip_runtime.h>
#include <hip/hip_bf16.h>

// EmbeddingBag(mode='sum', include_last_offset=True) fused with (F,B,D)->(B,F,D).
// F=26, B=4096, D=64, NUM_BAGS=106496, avg bag len ~19.7 (row-weighted ~39).
//
// One wave per bag. Indices prefetched 64-at-a-time with ONE coalesced load,
// broadcast via __shfl in wave-uniform control flow. Main loop: 16-row blocks,
// 4 independent accumulator chains (4 unconditional float4 row-loads in
// flight per iteration), then an 8-row block, then a predicated 4-row tail.
// Row addresses computed as 32-bit element offsets (VOCAB*64 < 2^31).

#define F_FEAT 26
#define B_BATCH 4096
#define D_DIM 64
#define NUM_BAGS (F_FEAT * B_BATCH)

typedef float f32x4 __attribute__((ext_vector_type(4)));

__global__ __launch_bounds__(256) void embag_sum_kernel(
    const int* __restrict__ values,
    const int* __restrict__ offsets,
    const float* __restrict__ weight,
    float* __restrict__ out)
{
    const int wave = (int)((blockIdx.x * blockDim.x + threadIdx.x) >> 6);
    if (wave >= NUM_BAGS) return;
    const int lane = (int)(threadIdx.x & 63);
    const int rgrp = lane >> 4;      // 0..3 : row slot within a 4-row group set
    const int col4e = (lane & 15) << 2;  // element offset of this lane's float4

    const int start = offsets[wave];
    const int len   = offsets[wave + 1] - start;
    if (len <= 0) {
        if (rgrp == 0) {
            const int f = wave >> 12;
            const int b = wave & (B_BATCH - 1);
            f32x4 z = {0.f, 0.f, 0.f, 0.f};
            f32x4* o = reinterpret_cast<f32x4*>(out + ((size_t)b * F_FEAT + f) * D_DIM);
            __builtin_nontemporal_store(z, &o[col4e >> 2]);
        }
        return;
    }

    f32x4 acc0 = {0.f, 0.f, 0.f, 0.f};
    f32x4 acc1 = {0.f, 0.f, 0.f, 0.f};
    f32x4 acc2 = {0.f, 0.f, 0.f, 0.f};
    f32x4 acc3 = {0.f, 0.f, 0.f, 0.f};

    for (int base = 0; base < len; base += 64) {
        const int chunk = min(64, len - base);
        // Coalesced: clamp instead of predicate (duplicate reads are harmless).
        const int myidx = values[start + min(base + lane, len - 1)];

        int rb = 0;
        const int nfull16 = chunk & ~15;
        // 16-row blocks: 4 unconditional loads in flight, no exec-mask ops.
        for (; rb < nfull16; rb += 16) {
            const int i0 = __shfl(myidx, rb + rgrp,      64);
            const int i1 = __shfl(myidx, rb + rgrp + 4,  64);
            const int i2 = __shfl(myidx, rb + rgrp + 8,  64);
            const int i3 = __shfl(myidx, rb + rgrp + 12, 64);
            const f32x4 w0 = *reinterpret_cast<const f32x4*>(weight + (unsigned)(i0 * D_DIM + col4e));
            const f32x4 w1 = *reinterpret_cast<const f32x4*>(weight + (unsigned)(i1 * D_DIM + col4e));
            const f32x4 w2 = *reinterpret_cast<const f32x4*>(weight + (unsigned)(i2 * D_DIM + col4e));
            const f32x4 w3 = *reinterpret_cast<const f32x4*>(weight + (unsigned)(i3 * D_DIM + col4e));
            acc0 += w0; acc1 += w1; acc2 += w2; acc3 += w3;
        }
        // One 8-row block if >=8 rows remain.
        if (chunk - rb >= 8) {
            const int i0 = __shfl(myidx, rb + rgrp,     64);
            const int i1 = __shfl(myidx, rb + rgrp + 4, 64);
            const f32x4 w0 = *reinterpret_cast<const f32x4*>(weight + (unsigned)(i0 * D_DIM + col4e));
            const f32x4 w1 = *reinterpret_cast<const f32x4*>(weight + (unsigned)(i1 * D_DIM + col4e));
            acc0 += w0; acc1 += w1;
            rb += 8;
        }
        // Predicated tail (<8 rows), shfl kept wave-uniform.
        if (rb < chunk) {
            const int r0 = rb + rgrp;
            const int r1 = rb + rgrp + 4;
            const int i0 = __shfl(myidx, r0, 64);
            const int i1 = __shfl(myidx, r1, 64);
            if (r0 < chunk)
                acc0 += *reinterpret_cast<const f32x4*>(weight + (unsigned)(i0 * D_DIM + col4e));
            if (r1 < chunk)
                acc1 += *reinterpret_cast<const f32x4*>(weight + (unsigned)(i1 * D_DIM + col4e));
        }
    }

    acc0 += acc1; acc2 += acc3; acc0 += acc2;

    // Reduce the 4 row-groups (lane bits 4 and 5) onto row-group 0.
    #pragma unroll
    for (int m = 16; m <= 32; m <<= 1) {
        acc0.x += __shfl_xor(acc0.x, m, 64);
        acc0.y += __shfl_xor(acc0.y, m, 64);
        acc0.z += __shfl_xor(acc0.z, m, 64);
        acc0.w += __shfl_xor(acc0.w, m, 64);
    }

    if (rgrp == 0) {
        const int f = wave >> 12;        // wave / B_BATCH (B=4096)
        const int b = wave & (B_BATCH - 1);
        f32x4* o = reinterpret_cast<f32x4*>(
            out + ((size_t)b * F_FEAT + f) * D_DIM);
        __builtin_nontemporal_store(acc0, &o[col4e >> 2]);
    }
}

extern "C" void kernel_launch(void* const* d_in, const int* in_sizes, int n_in,
                              void* d_out, int out_size, void* d_ws, size_t ws_size,
                              hipStream_t stream) {
    const int*   values  = (const int*)d_in[0];
    const int*   offsets = (const int*)d_in[1];
    const float* weight  = (const float*)d_in[2];
    float*       out     = (float*)d_out;

    const int waves_per_block = 256 / 64;
    const int grid = (NUM_BAGS + waves_per_block - 1) / waves_per_block;
    embag_sum_kernel<<<grid, 256, 0, stream>>>(values, offsets, weight, out);
}